// Round 4
// baseline (147.643 us; speedup 1.0000x reference)
//
#include <hip/hip_runtime.h>
#include <hip/hip_bf16.h>
#include <cstddef>

// B=16, N=512, C_SIZE=512, STRIDE=8 -> C=64, M=4096, out [16, 513, 4096] fp32.
constexpr int NPT = 512;
constexpr int C   = 64;
constexpr int M   = C * C;          // 4096
constexpr int NP1 = NPT + 1;        // 513
constexpr float BG_RATIO = 0.15f;
constexpr float EPS = 1e-5f;
// exp(-d/128) == exp2(d * CEXP), CEXP = -log2(e)/128
constexpr float CEXP = -0.011271055f;

typedef float f4 __attribute__((ext_vector_type(4)));

// Single kernel (R2 structure — faster than the 2-kernel split), with
// NON-TEMPORAL stores for all d_out traffic. Theory: d_out/d_ws are
// re-poisoned (0xAA, 537 MB) right before each timed launch, leaving L2/L3
// full of dirty lines; regular stores allocate -> evict poison -> extra HBM
// writeback serialized with our writes (~60 us observed vs 21 us roofline,
// pattern-independent across R1-R3). NT stores bypass allocation.
//
// Block = 256 threads = 4 waves per (b, i) grid row.
// Thread t: jg = t&15 -> owns pixels j = 4*jg..4*jg+3 (float4 stores);
//           pc = t>>4 -> owns points [32*pc, 32*pc+32).
// No max-shift needed: logits <= 0 and min(mind,bg) <= 76.8^2 so the softmax
// denominator >= exp2(76.8^2*CEXP) — safe fp32 (absmax 3e-5 verified R2/R3).
__global__ __launch_bounds__(256) void pp_kernel(
    const float* __restrict__ points,   // [B, NPT, 2] (x, y)
    const float* __restrict__ st,       // [B]
    float* __restrict__ out)            // [B, NP1, M]
{
    const int b    = blockIdx.x >> 6;
    const int i    = blockIdx.x & 63;
    const int t    = threadIdx.x;
    const int lane = t & 63;
    const int w    = t >> 6;
    const int jg   = t & 15;
    const int pc   = t >> 4;

    const float cy  = (float)(i * 8 + 4);
    const float cx0 = (float)(jg * 32 + 4);
    const float cx1 = cx0 + 8.0f;
    const float cx2 = cx0 + 16.0f;
    const float cx3 = cx0 + 24.0f;

    __shared__ float2 pts[NPT];          // 4 KB
    __shared__ float4 redmin[4][16];     // [wave][jg]
    __shared__ float4 redsum[4][16];
    __shared__ float  rs[C];             // 1/denominator per pixel
    __shared__ float  bgs[C];            // bg distance per pixel

    const float2* pb = (const float2*)(points + (size_t)b * NPT * 2);
    for (int p = t; p < NPT; p += 256) pts[p] = pb[p];
    __syncthreads();

    const int p0 = pc * 32;

    // ---- Fused pass: min distance AND sum of exp over this chunk ----
    float4 mn = make_float4(3.4e38f, 3.4e38f, 3.4e38f, 3.4e38f);
    float4 sm = make_float4(0.f, 0.f, 0.f, 0.f);
    #pragma unroll 4
    for (int k = 0; k < 32; ++k) {
        float2 xy = pts[p0 + k];
        float dy  = xy.y - cy;
        float dy2 = dy * dy;
        float dx0 = xy.x - cx0, dx1 = xy.x - cx1, dx2 = xy.x - cx2, dx3 = xy.x - cx3;
        float d0 = fmaf(dx0, dx0, dy2);
        float d1 = fmaf(dx1, dx1, dy2);
        float d2 = fmaf(dx2, dx2, dy2);
        float d3 = fmaf(dx3, dx3, dy2);
        mn.x = fminf(mn.x, d0); mn.y = fminf(mn.y, d1);
        mn.z = fminf(mn.z, d2); mn.w = fminf(mn.w, d3);
        sm.x += exp2f(d0 * CEXP); sm.y += exp2f(d1 * CEXP);
        sm.z += exp2f(d2 * CEXP); sm.w += exp2f(d3 * CEXP);
    }

    // Reduce over the 4 point-chunks resident in this wave (lane bits 4,5).
    #pragma unroll
    for (int off = 16; off <= 32; off <<= 1) {
        mn.x = fminf(mn.x, __shfl_xor(mn.x, off));
        mn.y = fminf(mn.y, __shfl_xor(mn.y, off));
        mn.z = fminf(mn.z, __shfl_xor(mn.z, off));
        mn.w = fminf(mn.w, __shfl_xor(mn.w, off));
        sm.x += __shfl_xor(sm.x, off);
        sm.y += __shfl_xor(sm.y, off);
        sm.z += __shfl_xor(sm.z, off);
        sm.w += __shfl_xor(sm.w, off);
    }
    if (lane < 16) { redmin[w][lane] = mn; redsum[w][lane] = sm; }
    __syncthreads();

    // Final cross-wave reduce + bg + reciprocal denominator (64 threads).
    if (t < C) {
        const float* rm = (const float*)redmin;   // [4][64] floats
        const float* rq = (const float*)redsum;
        float m0 = fminf(fminf(rm[t], rm[64 + t]), fminf(rm[128 + t], rm[192 + t]));
        float s0 = (rq[t] + rq[64 + t]) + (rq[128 + t] + rq[192 + t]);
        float ss = st[b] * BG_RATIO;
        float bg = (ss * ss) / (m0 + EPS);
        float tot = s0 + exp2f(bg * CEXP);
        bgs[t] = bg;
        rs[t]  = 1.0f / tot;
    }
    __syncthreads();

    const float4 r4 = *(const float4*)&rs[jg * 4];

    // ---- Store pass: recompute exp, normalize, NT float4 stream out ----
    float* ob = out + (size_t)b * NP1 * M + (size_t)p0 * M + i * C + jg * 4;
    #pragma unroll 4
    for (int k = 0; k < 32; ++k) {
        float2 xy = pts[p0 + k];
        float dy  = xy.y - cy;
        float dy2 = dy * dy;
        float dx0 = xy.x - cx0, dx1 = xy.x - cx1, dx2 = xy.x - cx2, dx3 = xy.x - cx3;
        f4 v;
        v.x = exp2f(fmaf(dx0, dx0, dy2) * CEXP) * r4.x;
        v.y = exp2f(fmaf(dx1, dx1, dy2) * CEXP) * r4.y;
        v.z = exp2f(fmaf(dx2, dx2, dy2) * CEXP) * r4.z;
        v.w = exp2f(fmaf(dx3, dx3, dy2) * CEXP) * r4.w;
        __builtin_nontemporal_store(v, (f4*)(ob + (size_t)k * M));
    }

    // Background row (p = NPT): 64 consecutive floats per block.
    if (t < C) {
        float val = exp2f(bgs[t] * CEXP) * rs[t];
        __builtin_nontemporal_store(
            val, out + (size_t)b * NP1 * M + (size_t)NPT * M + i * C + t);
    }
}

extern "C" void kernel_launch(void* const* d_in, const int* in_sizes, int n_in,
                              void* d_out, int out_size, void* d_ws, size_t ws_size,
                              hipStream_t stream) {
    const float* points = (const float*)d_in[0];   // [16, 512, 2] fp32
    const float* st     = (const float*)d_in[1];   // [16] fp32
    float* out          = (float*)d_out;           // [16, 513, 4096] fp32

    const int B = in_sizes[1];                     // 16
    dim3 grid(B * C);                              // 1024 blocks: (b*64 + i)
    dim3 block(256);
    pp_kernel<<<grid, block, 0, stream>>>(points, st, out);
}